// Round 24
// baseline (442.607 us; speedup 1.0000x reference)
//
#include <hip/hip_runtime.h>
#include <stdint.h>

// ---------------- types ----------------
typedef __bf16 bf16x8 __attribute__((ext_vector_type(8)));
typedef float f32x4 __attribute__((ext_vector_type(4)));
typedef unsigned short u16x8 __attribute__((ext_vector_type(8)));
typedef unsigned short u16x4 __attribute__((ext_vector_type(4)));
typedef unsigned int u32x2 __attribute__((ext_vector_type(2)));
typedef float fvec4 __attribute__((ext_vector_type(4)));

__device__ __forceinline__ unsigned short f2b(float f) {
  unsigned u = __builtin_bit_cast(unsigned, f);
  return (unsigned short)((u + 0x7fffu + ((u >> 16) & 1u)) >> 16);
}

__device__ __forceinline__ bf16x8 ldfrag(const unsigned short* p) {
  return __builtin_bit_cast(bf16x8, *(const u16x8*)p);
}

__device__ __forceinline__ float fexp2(float x) {
  float r;
  asm("v_exp_f32 %0, %1" : "=v"(r) : "v"(x));
  return r;
}

__device__ __forceinline__ unsigned cvtpk(float a, float b) {
  unsigned r;
  asm("v_cvt_pk_bf16_f32 %0, %1, %2" : "=v"(r) : "v"(a), "v"(b));
  return r;
}

// global->LDS direct load (16B per lane; LDS dest = wave base + lane*16)
__device__ __forceinline__ void gload_lds16(const void* g, void* l) {
  auto gp = reinterpret_cast<const __attribute__((address_space(1))) void*>(
      reinterpret_cast<uintptr_t>(g));
  auto lp = reinterpret_cast<__attribute__((address_space(3))) void*>(
      reinterpret_cast<uintptr_t>(l));
  __builtin_amdgcn_global_load_lds(gp, lp, 16, 0, 0);
}

// ---------------- weight transpose+cast: W[K][N] f32 -> Wt[N][K] bf16 ----------------
__global__ void transpose_cast(const float* __restrict__ W, unsigned short* __restrict__ Wt,
                               int K, int N) {
  __shared__ float tile[32][33];
  const int n0 = blockIdx.x * 32, k0 = blockIdx.y * 32;
  const int tx = threadIdx.x, ty = threadIdx.y;  // (32,8)
#pragma unroll
  for (int j = 0; j < 4; ++j)
    tile[ty + j * 8][tx] = W[(size_t)(k0 + ty + j * 8) * N + n0 + tx];
  __syncthreads();
#pragma unroll
  for (int j = 0; j < 4; ++j)
    Wt[(size_t)(n0 + ty + j * 8) * K + k0 + tx] = f2b(tile[tx][ty + j * 8]);
}

// ---------------- LayerNorm: fp32 row(1024) -> bf16 ----------------
__global__ void ln_kernel(const float* __restrict__ X, const float* __restrict__ g,
                          const float* __restrict__ be, unsigned short* __restrict__ H) {
  const int row = (blockIdx.x * blockDim.x + threadIdx.x) >> 6;
  const int l = threadIdx.x & 63;
  const float* xr = X + (size_t)row * 1024;
  fvec4 v[4];
  float s = 0.f, sq = 0.f;
#pragma unroll
  for (int i = 0; i < 4; ++i) {
    v[i] = *(const fvec4*)(xr + i * 256 + l * 4);
#pragma unroll
    for (int j = 0; j < 4; ++j) { s += v[i][j]; sq += v[i][j] * v[i][j]; }
  }
#pragma unroll
  for (int off = 32; off >= 1; off >>= 1) {
    s += __shfl_xor(s, off);
    sq += __shfl_xor(sq, off);
  }
  const float mean = s * (1.f / 1024.f);
  const float var = sq * (1.f / 1024.f) - mean * mean;
  const float rstd = rsqrtf(var + 1e-5f);
#pragma unroll
  for (int i = 0; i < 4; ++i) {
    const int col = i * 256 + l * 4;
    fvec4 gg = *(const fvec4*)(g + col);
    fvec4 bb = *(const fvec4*)(be + col);
    u16x4 o;
#pragma unroll
    for (int j = 0; j < 4; ++j) o[j] = f2b((v[i][j] - mean) * rstd * gg[j] + bb[j]);
    *(u16x4*)(H + (size_t)row * 1024 + col) = o;
  }
}

// ---------------- shared-B persistent GEMM: 128x256 tile, BK=64, NBUF=3 (R21) ----------
template <int EPI>
__global__ __launch_bounds__(512, 1) void gemmS(
    const unsigned short* __restrict__ A, const unsigned short* __restrict__ Bt,
    const float* __restrict__ bias, const float* __restrict__ resid,
    float* __restrict__ Cf, unsigned short* __restrict__ Cb,
    unsigned short* __restrict__ pK, unsigned short* __restrict__ pVT,
    int N, int K, int ntiles) {
  constexpr int ASZ = 16384;   // 128 rows x 128 B
  constexpr int BSZ = 32768;   // 256 rows x 128 B
  constexpr int BUFSZ = ASZ + BSZ;  // 48 KB
  __shared__ __align__(16) char lds[3 * BUFSZ];  // 144 KB

  const int tid = threadIdx.x;
  const int w = tid >> 6, l = tid & 63;
  const int wr = w >> 2, wc = w & 3;  // 2M x 4N
  const int kg = l >> 4, fr = l & 15;
  const int nblk = (int)gridDim.x;

  int Aoff[2][4], Boff[2][4];
#pragma unroll
  for (int kk = 0; kk < 2; ++kk) {
#pragma unroll
    for (int m = 0; m < 4; ++m) {
      const int r = wr * 64 + m * 16 + fr;
      Aoff[kk][m] = r * 128 + (((kk * 4 + kg) ^ (r & 7)) << 4);
    }
#pragma unroll
    for (int n = 0; n < 4; ++n) {
      const int rn = wc * 64 + n * 16 + fr;
      Boff[kk][n] = ASZ + rn * 128 + (((kk * 4 + kg) ^ (rn & 7)) << 4);
    }
  }

  for (int tl = (int)blockIdx.x; tl < ntiles; tl += nblk) {
    if (tl != (int)blockIdx.x) {
      asm volatile("s_waitcnt vmcnt(0) lgkmcnt(0)" ::: "memory");
      __builtin_amdgcn_s_barrier();
    }
    // L2-fitting tile map: per 256-tile round, XCD x covers 8 A-panels x 4 B-slabs (4MB)
    const int round = tl >> 8;
    const int i = tl & 255;
    const int xcd = i & 7;
    const int s = i >> 3;
    const size_t am0 = (size_t)(xcd * 8 + (s >> 2)) * 128;
    const size_t bn0 = (size_t)(round * 4 + (s & 3)) * 256;

    const char* src[6];
#pragma unroll
    for (int u = 0; u < 2; ++u) {
      const int flat = u * 512 + tid;
      const int row = flat >> 3, c = flat & 7;
      src[u] = (const char*)(A + (am0 + row) * K) + ((c ^ (row & 7)) << 4);
    }
#pragma unroll
    for (int u = 0; u < 4; ++u) {
      const int flat = u * 512 + tid;
      const int row = flat >> 3, c = flat & 7;
      src[2 + u] = (const char*)(Bt + (bn0 + row) * K) + ((c ^ (row & 7)) << 4);
    }

    f32x4 acc[4][4];
#pragma unroll
    for (int m = 0; m < 4; ++m)
#pragma unroll
      for (int n = 0; n < 4; ++n) acc[m][n] = (f32x4){0.f, 0.f, 0.f, 0.f};

    // staging split into three 2-load chunks (A,A | B0,B1 | B2,B3)
    auto stage_a = [&](int sb) {
      char* Ld = lds + sb * BUFSZ;
      gload_lds16(src[0], Ld + tid * 16);
      src[0] += 128;
      gload_lds16(src[1], Ld + 8192 + tid * 16);
      src[1] += 128;
    };
    auto stage_b = [&](int sb) {
      char* Ld = lds + sb * BUFSZ;
      gload_lds16(src[2], Ld + ASZ + tid * 16);
      src[2] += 128;
      gload_lds16(src[3], Ld + ASZ + 8192 + tid * 16);
      src[3] += 128;
    };
    auto stage_c = [&](int sb) {
      char* Ld = lds + sb * BUFSZ;
      gload_lds16(src[4], Ld + ASZ + 16384 + tid * 16);
      src[4] += 128;
      gload_lds16(src[5], Ld + ASZ + 24576 + tid * 16);
      src[5] += 128;
    };

    const int NT = K >> 6;  // K-tiles of 64
    stage_a(0);
    stage_b(0);
    stage_c(0);
    stage_a(1);
    stage_b(1);
    stage_c(1);
    asm volatile("s_waitcnt vmcnt(6)" ::: "memory");
    __builtin_amdgcn_s_barrier();

    int cb0 = 0, sb = 2;
    for (int kt = 0; kt < NT; ++kt) {
      const bool pre = (kt + 2 < NT);
      if (pre) stage_a(sb);
      // kk0 cluster (stage_b issues in its MFMA shadow)
      {
        bf16x8 af[4], bf[4];
#pragma unroll
        for (int m = 0; m < 4; ++m)
          af[m] = ldfrag((const unsigned short*)(lds + cb0 + Aoff[0][m]));
#pragma unroll
        for (int n = 0; n < 4; ++n)
          bf[n] = ldfrag((const unsigned short*)(lds + cb0 + Boff[0][n]));
        if (pre) stage_b(sb);
        __builtin_amdgcn_s_setprio(1);
#pragma unroll
        for (int m = 0; m < 4; ++m)
#pragma unroll
          for (int n = 0; n < 4; ++n)
            acc[m][n] = __builtin_amdgcn_mfma_f32_16x16x32_bf16(af[m], bf[n], acc[m][n], 0, 0, 0);
        __builtin_amdgcn_s_setprio(0);
      }
      // kk1 cluster (stage_c issues in its MFMA shadow)
      {
        bf16x8 af[4], bf[4];
#pragma unroll
        for (int m = 0; m < 4; ++m)
          af[m] = ldfrag((const unsigned short*)(lds + cb0 + Aoff[1][m]));
#pragma unroll
        for (int n = 0; n < 4; ++n)
          bf[n] = ldfrag((const unsigned short*)(lds + cb0 + Boff[1][n]));
        if (pre) stage_c(sb);
        __builtin_amdgcn_s_setprio(1);
#pragma unroll
        for (int m = 0; m < 4; ++m)
#pragma unroll
          for (int n = 0; n < 4; ++n)
            acc[m][n] = __builtin_amdgcn_mfma_f32_16x16x32_bf16(af[m], bf[n], acc[m][n], 0, 0, 0);
        __builtin_amdgcn_s_setprio(0);
      }
      if (pre) {
        asm volatile("s_waitcnt vmcnt(6)" ::: "memory");  // tile t+1 published
        __builtin_amdgcn_s_barrier();
      } else if (kt + 1 < NT) {
        asm volatile("s_waitcnt vmcnt(0)" ::: "memory");
        __builtin_amdgcn_s_barrier();
      }
      cb0 += BUFSZ;
      if (cb0 == 3 * BUFSZ) cb0 = 0;
      sb += 1;
      if (sb == 3) sb = 0;
    }

    // epilogue
#pragma unroll
    for (int m = 0; m < 4; ++m) {
      const size_t row0 = am0 + wr * 64 + m * 16 + kg * 4;
#pragma unroll
      for (int n = 0; n < 4; ++n) {
        const size_t col = bn0 + wc * 64 + n * 16 + fr;
        if (EPI == 3) {
          if (bn0 < 1024) {
#pragma unroll
            for (int r = 0; r < 4; ++r) Cb[(row0 + r) * 1024 + col] = f2b(acc[m][n][r]);
          } else if (bn0 < 2048) {
#pragma unroll
            for (int r = 0; r < 4; ++r) pK[(row0 + r) * 1024 + col - 1024] = f2b(acc[m][n][r]);
          } else {
            const int c2 = (int)col - 2048;
            const int hh = c2 >> 6, dd = c2 & 63;
            const int bb = (int)(row0 >> 11), tt = (int)(row0 & 2047);
            u16x4 pv;
#pragma unroll
            for (int r = 0; r < 4; ++r) pv[r] = f2b(acc[m][n][r]);
            *(u16x4*)(pVT + (((size_t)bb * 16 + hh) * 64 + dd) * 2048 + tt) = pv;
          }
        } else {
          const float bv = (EPI >= 1) ? bias[col] : 0.f;
#pragma unroll
          for (int r = 0; r < 4; ++r) {
            const size_t idx = (row0 + r) * N + col;
            float v = acc[m][n][r] + bv;
            if (EPI == 1) v = fmaxf(v, 0.f);
            if (EPI == 2) {
              Cf[idx] = v + resid[idx];
            } else {
              Cb[idx] = f2b(v);
            }
          }
        }
      }
    }
  }
}

// ---------------- fused causal attention: 8 waves x 32q (TLP over ILP) ----------------
// R24: same 256 q-rows/block and K-ring, but 8 waves of 32q each. Per-wave VGPR
// halves (o[2][4], bq[2][2]) -> ~100 VGPR -> 4 waves/SIMD via launch_bounds(512,4).
// K staged by all 512 threads: ONE gload per 8KB buffer; counted vmcnt(1) steady.
#define PSTR 72
#define SC2 0.18033688f  /* 0.125 * log2(e) */
__global__ __launch_bounds__(512, 4) void attn_kernel(const unsigned short* __restrict__ Qb,
                                                      const unsigned short* __restrict__ Kb,
                                                      const unsigned short* __restrict__ VT,
                                                      unsigned short* __restrict__ ATT) {
  __shared__ __align__(16) char ldsK[3 * 8192];
  __shared__ __align__(16) unsigned short Pl[8][32 * PSTR];
  const int tid = threadIdx.x;
  const int w = tid >> 6, l = tid & 63;  // 8 waves
  const int kg = l >> 4, fr = l & 15;
  const int bh = blockIdx.x;
  const int b = bh >> 4, h = bh & 15;
  const int yy = (int)blockIdx.y;
  const int qt = (yy < 4) ? 7 - yy : yy - 4;
  const int q0 = qt * 256 + w * 32;  // wave's 32 q-rows
  const size_t rbase = (size_t)b * 2048;
  const unsigned short* vtb = VT + (size_t)bh * 64 * 2048;
  const f32x4 fz = {0.f, 0.f, 0.f, 0.f};

  // K staging: 512 threads cover the full 64x64 bf16 tile (8192B) in one gload each
  const int rowoff = tid >> 3;                        // 0..63
  const int cbsw = ((tid & 7) * 16) ^ ((rowoff & 7) << 4);
  const char* ksrc = (const char*)(Kb + rbase * 1024 + h * 64) + (size_t)rowoff * 2048 + cbsw;

  int koff[4][2];
#pragma unroll
  for (int sg = 0; sg < 4; ++sg)
#pragma unroll
    for (int c = 0; c < 2; ++c)
      koff[sg][c] = (sg * 16 + fr) * 128 + ((c * 64 + kg * 16) ^ ((fr & 7) << 4));

  bf16x8 bq[2][2];
#pragma unroll
  for (int qg = 0; qg < 2; ++qg) {
    const unsigned short* qrow = Qb + (rbase + q0 + qg * 16 + fr) * 1024 + h * 64;
#pragma unroll
    for (int c = 0; c < 2; ++c) bq[qg][c] = ldfrag(qrow + c * 32 + kg * 8);
  }

  f32x4 o[2][4];
#pragma unroll
  for (int qg = 0; qg < 2; ++qg)
#pragma unroll
    for (int nd = 0; nd < 4; ++nd) o[qg][nd] = (f32x4){0.f, 0.f, 0.f, 0.f};
  float m_run2[2] = {-1e30f, -1e30f};
  float l_run[2] = {0.f, 0.f};

  auto stage = [&](int t, int sbuf) {
    gload_lds16(ksrc + (size_t)(t * 64) * 2048, ldsK + sbuf * 8192 + tid * 16);
  };

  auto softmax_qg = [&](int qg, int s0, f32x4 (&stq)[4]) -> float {
    const int qa = q0 + qg * 16 + fr;
    float vals[16];
    if (s0 + 63 <= q0 + qg * 16) {
#pragma unroll
      for (int sg = 0; sg < 4; ++sg)
#pragma unroll
        for (int r = 0; r < 4; ++r) vals[sg * 4 + r] = stq[sg][r];
    } else {
#pragma unroll
      for (int sg = 0; sg < 4; ++sg)
#pragma unroll
        for (int r = 0; r < 4; ++r) {
          const int sa = s0 + sg * 16 + kg * 4 + r;
          vals[sg * 4 + r] = (sa > qa) ? -1e30f : stq[sg][r];
        }
    }
    float m5[5];
#pragma unroll
    for (int i = 0; i < 5; ++i)
      m5[i] = fmaxf(fmaxf(vals[3 * i], vals[3 * i + 1]), vals[3 * i + 2]);
    const float vmax =
        fmaxf(fmaxf(fmaxf(m5[0], m5[1]), m5[2]), fmaxf(fmaxf(m5[3], m5[4]), vals[15]));
    const float tm2 = vmax * SC2;
    if (__any(tm2 > m_run2[qg] + 8.f)) {
      float tmax2 = tm2;
      tmax2 = fmaxf(tmax2, __shfl_xor(tmax2, 16));
      tmax2 = fmaxf(tmax2, __shfl_xor(tmax2, 32));
      const float m_new2 = fmaxf(m_run2[qg], tmax2);
      const float alpha = fexp2(m_run2[qg] - m_new2);
      m_run2[qg] = m_new2;
      l_run[qg] *= alpha;
      float al[4];
#pragma unroll
      for (int r = 0; r < 4; ++r) al[r] = __shfl(alpha, kg * 4 + r);
#pragma unroll
      for (int nd = 0; nd < 4; ++nd)
#pragma unroll
        for (int r = 0; r < 4; ++r) o[qg][nd][r] *= al[r];
    }
    const float nm2 = -m_run2[qg];
    float psum = 0.f;
    unsigned pk[8];
#pragma unroll
    for (int i = 0; i < 8; ++i) {
      const float p0 = fexp2(__builtin_fmaf(vals[2 * i], SC2, nm2));
      const float p1 = fexp2(__builtin_fmaf(vals[2 * i + 1], SC2, nm2));
      psum += p0 + p1;
      pk[i] = cvtpk(p0, p1);
    }
#pragma unroll
    for (int sg = 0; sg < 4; ++sg) {
      u32x2 w2 = {pk[2 * sg], pk[2 * sg + 1]};
      *(u32x2*)(&Pl[w][(qg * 16 + fr) * PSTR + sg * 16 + kg * 4]) = w2;
    }
    return psum;
  };

  auto compute = [&](int s0, int cbb) {
    if (s0 > q0 + 31) return;  // wave-uniform causal skip
    bf16x8 vb[4][2];
#pragma unroll
    for (int nd = 0; nd < 4; ++nd)
#pragma unroll
      for (int ks = 0; ks < 2; ++ks)
        vb[nd][ks] = ldfrag(vtb + (size_t)(nd * 16 + fr) * 2048 + s0 + ks * 32 + kg * 8);

    f32x4 st[4][2];
#pragma unroll
    for (int sg = 0; sg < 4; ++sg) {
      const bf16x8 ka0 = ldfrag((const unsigned short*)(ldsK + cbb + koff[sg][0]));
      const bf16x8 ka1 = ldfrag((const unsigned short*)(ldsK + cbb + koff[sg][1]));
#pragma unroll
      for (int qh = 0; qh < 2; ++qh)
        st[sg][qh] = __builtin_amdgcn_mfma_f32_16x16x32_bf16(
            ka1, bq[qh][1],
            __builtin_amdgcn_mfma_f32_16x16x32_bf16(ka0, bq[qh][0], fz, 0, 0, 0), 0, 0, 0);
    }

    float psv[2];
#pragma unroll
    for (int qh = 0; qh < 2; ++qh) {
      f32x4 stq[4];
#pragma unroll
      for (int sg = 0; sg < 4; ++sg) stq[sg] = st[sg][qh];
      psv[qh] = softmax_qg(qh, s0, stq);
    }

    {
      const float a0 = __shfl_xor(psv[0], 16);
      const float a1 = __shfl_xor(psv[1], 16);
      psv[0] += a0;
      psv[1] += a1;
      const float b0 = __shfl_xor(psv[0], 32);
      const float b1 = __shfl_xor(psv[1], 32);
      l_run[0] += psv[0] + b0;
      l_run[1] += psv[1] + b1;
    }

#pragma unroll
    for (int qg = 0; qg < 2; ++qg)
#pragma unroll
      for (int ks = 0; ks < 2; ++ks) {
        const bf16x8 pa = ldfrag(&Pl[w][(qg * 16 + fr) * PSTR + ks * 32 + kg * 8]);
#pragma unroll
        for (int nd = 0; nd < 4; ++nd)
          o[qg][nd] = __builtin_amdgcn_mfma_f32_16x16x32_bf16(pa, vb[nd][ks], o[qg][nd], 0, 0, 0);
      }
  };

  const int NT = 4 * qt + 4;
  stage(0, 0);
  stage(1, 1);
  asm volatile("s_waitcnt vmcnt(1)" ::: "memory");
  __builtin_amdgcn_s_barrier();
  int cb = 0, sb = 2;
  for (int t = 0; t < NT; ++t) {
    if (t + 2 < NT) stage(t + 2, sb);
    compute(t * 64, cb * 8192);
    if (t + 2 < NT) {
      asm volatile("s_waitcnt vmcnt(1)" ::: "memory");
      __builtin_amdgcn_s_barrier();
    } else if (t + 1 < NT) {
      asm volatile("s_waitcnt vmcnt(0)" ::: "memory");
      __builtin_amdgcn_s_barrier();
    }
    cb += 1; if (cb == 3) cb = 0;
    sb += 1; if (sb == 3) sb = 0;
  }

#pragma unroll
  for (int qg = 0; qg < 2; ++qg) {
    const float li = __builtin_amdgcn_rcpf(l_run[qg]);
    float linv[4];
#pragma unroll
    for (int r = 0; r < 4; ++r) linv[r] = __shfl(li, kg * 4 + r);
#pragma unroll
    for (int nd = 0; nd < 4; ++nd)
#pragma unroll
      for (int r = 0; r < 4; ++r) {
        const size_t row = rbase + q0 + qg * 16 + kg * 4 + r;
        ATT[row * 1024 + h * 64 + nd * 16 + fr] = f2b(o[qg][nd][r] * linv[r]);
      }
  }
}

// ---------------- launch ----------------
extern "C" void kernel_launch(void* const* d_in, const int* in_sizes, int n_in, void* d_out,
                              int out_size, void* d_ws, size_t ws_size, hipStream_t stream) {
  const float* x = (const float*)d_in[0];
  const float* Wk = (const float*)d_in[1];
  const float* Wq = (const float*)d_in[2];
  const float* Wv = (const float*)d_in[3];
  const float* Wproj = (const float*)d_in[4];
  const float* bproj = (const float*)d_in[5];
  const float* W1 = (const float*)d_in[6];
  const float* b1 = (const float*)d_in[7];
  const float* W2 = (const float*)d_in[8];
  const float* b2 = (const float*)d_in[9];
  const float* g1 = (const float*)d_in[10];
  const float* beta1 = (const float*)d_in[11];
  const float* g2 = (const float*)d_in[12];
  const float* beta2 = (const float*)d_in[13];
  float* out = (float*)d_out;
  unsigned short* wsu = (unsigned short*)d_ws;

  const size_t o_qkvW = 0;                           // [3072][1024]
  const size_t o_projW = o_qkvW + 3072 * 1024;       // [1024][1024]
  const size_t o_W1 = o_projW + 1024 * 1024;         // [4096][1024]
  const size_t o_W2 = o_W1 + 4096 * 1024;            // [1024][4096]
  const size_t o_H = o_W2 + 1024 * 4096;             // [8192][1024]
  const size_t o_Q = o_H + (size_t)8192 * 1024;      // [8192][1024]
  const size_t o_K = o_Q + (size_t)8192 * 1024;      // [8192][1024]
  const size_t o_VT = o_K + (size_t)8192 * 1024;     // [64][64][2048]
  const size_t o_ATT = o_VT + (size_t)8192 * 1024;   // [8192][1024]
  const size_t o_FF1 = o_Q;                          // [8192][4096] (reuses Q,K,VT,ATT)

  dim3 tpb(32, 8);
  transpose_cast<<<dim3(32, 32), tpb, 0, stream>>>(Wq, wsu + o_qkvW, 1024, 1024);
  transpose_cast<<<dim3(32, 32), tpb, 0, stream>>>(Wk, wsu + o_qkvW + 1024 * 1024, 1024, 1024);
  transpose_cast<<<dim3(32, 32), tpb, 0, stream>>>(Wv, wsu + o_qkvW + 2 * 1024 * 1024, 1024, 1024);
  transpose_cast<<<dim3(32, 32), tpb, 0, stream>>>(Wproj, wsu + o_projW, 1024, 1024);
  transpose_cast<<<dim3(128, 32), tpb, 0, stream>>>(W1, wsu + o_W1, 1024, 4096);
  transpose_cast<<<dim3(32, 128), tpb, 0, stream>>>(W2, wsu + o_W2, 4096, 1024);

  ln_kernel<<<2048, 256, 0, stream>>>(x, g1, beta1, wsu + o_H);

  // QKV: 768 tiles, grid 256 x3 rounds, EPI3 splits Q/K/V^T
  gemmS<3><<<256, 512, 0, stream>>>(wsu + o_H, wsu + o_qkvW, nullptr, nullptr, nullptr,
                                    wsu + o_Q, wsu + o_K, wsu + o_VT, 3072, 1024, 768);

  attn_kernel<<<dim3(64, 8), 512, 0, stream>>>(wsu + o_Q, wsu + o_K, wsu + o_VT, wsu + o_ATT);

  // proj: 256 tiles, grid 256 x1 round
  gemmS<2><<<256, 512, 0, stream>>>(wsu + o_ATT, wsu + o_projW, bproj, x, out, nullptr,
                                    nullptr, nullptr, 1024, 1024, 256);

  ln_kernel<<<2048, 256, 0, stream>>>(out, g2, beta2, wsu + o_H);

  // FF1: 1024 tiles, grid 256 x4 rounds
  gemmS<1><<<256, 512, 0, stream>>>(wsu + o_H, wsu + o_W1, b1, nullptr, nullptr,
                                    wsu + o_FF1, nullptr, nullptr, 4096, 1024, 1024);

  // FF2: 256 tiles, grid 256 x1 round, K=4096 (NT=64)
  gemmS<2><<<256, 512, 0, stream>>>(wsu + o_FF1, wsu + o_W2, b2, out, out, nullptr,
                                    nullptr, nullptr, 1024, 4096, 256);
}

// Round 25
// 329.282 us; speedup vs baseline: 1.3442x; 1.3442x over previous
//
#include <hip/hip_runtime.h>
#include <stdint.h>

// ---------------- types ----------------
typedef __bf16 bf16x8 __attribute__((ext_vector_type(8)));
typedef float f32x4 __attribute__((ext_vector_type(4)));
typedef unsigned short u16x8 __attribute__((ext_vector_type(8)));
typedef unsigned short u16x4 __attribute__((ext_vector_type(4)));
typedef unsigned int u32x2 __attribute__((ext_vector_type(2)));
typedef float fvec4 __attribute__((ext_vector_type(4)));

__device__ __forceinline__ unsigned short f2b(float f) {
  unsigned u = __builtin_bit_cast(unsigned, f);
  return (unsigned short)((u + 0x7fffu + ((u >> 16) & 1u)) >> 16);
}

__device__ __forceinline__ bf16x8 ldfrag(const unsigned short* p) {
  return __builtin_bit_cast(bf16x8, *(const u16x8*)p);
}

__device__ __forceinline__ float fexp2(float x) {
  float r;
  asm("v_exp_f32 %0, %1" : "=v"(r) : "v"(x));
  return r;
}

__device__ __forceinline__ unsigned cvtpk(float a, float b) {
  unsigned r;
  asm("v_cvt_pk_bf16_f32 %0, %1, %2" : "=v"(r) : "v"(a), "v"(b));
  return r;
}

// global->LDS direct load (16B per lane; LDS dest = wave base + lane*16)
__device__ __forceinline__ void gload_lds16(const void* g, void* l) {
  auto gp = reinterpret_cast<const __attribute__((address_space(1))) void*>(
      reinterpret_cast<uintptr_t>(g));
  auto lp = reinterpret_cast<__attribute__((address_space(3))) void*>(
      reinterpret_cast<uintptr_t>(l));
  __builtin_amdgcn_global_load_lds(gp, lp, 16, 0, 0);
}

// ---------------- weight transpose+cast: W[K][N] f32 -> Wt[N][K] bf16 ----------------
__global__ void transpose_cast(const float* __restrict__ W, unsigned short* __restrict__ Wt,
                               int K, int N) {
  __shared__ float tile[32][33];
  const int n0 = blockIdx.x * 32, k0 = blockIdx.y * 32;
  const int tx = threadIdx.x, ty = threadIdx.y;  // (32,8)
#pragma unroll
  for (int j = 0; j < 4; ++j)
    tile[ty + j * 8][tx] = W[(size_t)(k0 + ty + j * 8) * N + n0 + tx];
  __syncthreads();
#pragma unroll
  for (int j = 0; j < 4; ++j)
    Wt[(size_t)(n0 + ty + j * 8) * K + k0 + tx] = f2b(tile[tx][ty + j * 8]);
}

// ---------------- LayerNorm: fp32 row(1024) -> bf16 ----------------
__global__ void ln_kernel(const float* __restrict__ X, const float* __restrict__ g,
                          const float* __restrict__ be, unsigned short* __restrict__ H) {
  const int row = (blockIdx.x * blockDim.x + threadIdx.x) >> 6;
  const int l = threadIdx.x & 63;
  const float* xr = X + (size_t)row * 1024;
  fvec4 v[4];
  float s = 0.f, sq = 0.f;
#pragma unroll
  for (int i = 0; i < 4; ++i) {
    v[i] = *(const fvec4*)(xr + i * 256 + l * 4);
#pragma unroll
    for (int j = 0; j < 4; ++j) { s += v[i][j]; sq += v[i][j] * v[i][j]; }
  }
#pragma unroll
  for (int off = 32; off >= 1; off >>= 1) {
    s += __shfl_xor(s, off);
    sq += __shfl_xor(sq, off);
  }
  const float mean = s * (1.f / 1024.f);
  const float var = sq * (1.f / 1024.f) - mean * mean;
  const float rstd = rsqrtf(var + 1e-5f);
#pragma unroll
  for (int i = 0; i < 4; ++i) {
    const int col = i * 256 + l * 4;
    fvec4 gg = *(const fvec4*)(g + col);
    fvec4 bb = *(const fvec4*)(be + col);
    u16x4 o;
#pragma unroll
    for (int j = 0; j < 4; ++j) o[j] = f2b((v[i][j] - mean) * rstd * gg[j] + bb[j]);
    *(u16x4*)(H + (size_t)row * 1024 + col) = o;
  }
}

// ---------------- shared-B persistent GEMM: 128x256 tile, BK=64, NBUF=3 ----------------
// R21 (best): staging distributed 2+2+2 — 2 loads before kk0 ds_reads, 2 in kk0's MFMA
// shadow, 2 in kk1's MFMA shadow. All 6 issue before the tile-end vmcnt(6)+barrier.
// L2-fit tile map + race-fix drain at loop-top barrier (R16/R17).
// EPI 0: bf16. 1: +bias ReLU bf16. 2: +bias +resid f32. 3: QKV split (Q,K bf16; V^T).
template <int EPI>
__global__ __launch_bounds__(512, 1) void gemmS(
    const unsigned short* __restrict__ A, const unsigned short* __restrict__ Bt,
    const float* __restrict__ bias, const float* __restrict__ resid,
    float* __restrict__ Cf, unsigned short* __restrict__ Cb,
    unsigned short* __restrict__ pK, unsigned short* __restrict__ pVT,
    int N, int K, int ntiles) {
  constexpr int ASZ = 16384;   // 128 rows x 128 B
  constexpr int BSZ = 32768;   // 256 rows x 128 B
  constexpr int BUFSZ = ASZ + BSZ;  // 48 KB
  __shared__ __align__(16) char lds[3 * BUFSZ];  // 144 KB

  const int tid = threadIdx.x;
  const int w = tid >> 6, l = tid & 63;
  const int wr = w >> 2, wc = w & 3;  // 2M x 4N
  const int kg = l >> 4, fr = l & 15;
  const int nblk = (int)gridDim.x;

  int Aoff[2][4], Boff[2][4];
#pragma unroll
  for (int kk = 0; kk < 2; ++kk) {
#pragma unroll
    for (int m = 0; m < 4; ++m) {
      const int r = wr * 64 + m * 16 + fr;
      Aoff[kk][m] = r * 128 + (((kk * 4 + kg) ^ (r & 7)) << 4);
    }
#pragma unroll
    for (int n = 0; n < 4; ++n) {
      const int rn = wc * 64 + n * 16 + fr;
      Boff[kk][n] = ASZ + rn * 128 + (((kk * 4 + kg) ^ (rn & 7)) << 4);
    }
  }

  for (int tl = (int)blockIdx.x; tl < ntiles; tl += nblk) {
    if (tl != (int)blockIdx.x) {
      asm volatile("s_waitcnt vmcnt(0) lgkmcnt(0)" ::: "memory");
      __builtin_amdgcn_s_barrier();
    }
    // L2-fitting tile map: per 256-tile round, XCD x covers 8 A-panels x 4 B-slabs (4MB)
    const int round = tl >> 8;
    const int i = tl & 255;
    const int xcd = i & 7;
    const int s = i >> 3;
    const size_t am0 = (size_t)(xcd * 8 + (s >> 2)) * 128;
    const size_t bn0 = (size_t)(round * 4 + (s & 3)) * 256;

    const char* src[6];
#pragma unroll
    for (int u = 0; u < 2; ++u) {
      const int flat = u * 512 + tid;
      const int row = flat >> 3, c = flat & 7;
      src[u] = (const char*)(A + (am0 + row) * K) + ((c ^ (row & 7)) << 4);
    }
#pragma unroll
    for (int u = 0; u < 4; ++u) {
      const int flat = u * 512 + tid;
      const int row = flat >> 3, c = flat & 7;
      src[2 + u] = (const char*)(Bt + (bn0 + row) * K) + ((c ^ (row & 7)) << 4);
    }

    f32x4 acc[4][4];
#pragma unroll
    for (int m = 0; m < 4; ++m)
#pragma unroll
      for (int n = 0; n < 4; ++n) acc[m][n] = (f32x4){0.f, 0.f, 0.f, 0.f};

    // staging split into three 2-load chunks (A,A | B0,B1 | B2,B3)
    auto stage_a = [&](int sb) {
      char* Ld = lds + sb * BUFSZ;
      gload_lds16(src[0], Ld + tid * 16);
      src[0] += 128;
      gload_lds16(src[1], Ld + 8192 + tid * 16);
      src[1] += 128;
    };
    auto stage_b = [&](int sb) {
      char* Ld = lds + sb * BUFSZ;
      gload_lds16(src[2], Ld + ASZ + tid * 16);
      src[2] += 128;
      gload_lds16(src[3], Ld + ASZ + 8192 + tid * 16);
      src[3] += 128;
    };
    auto stage_c = [&](int sb) {
      char* Ld = lds + sb * BUFSZ;
      gload_lds16(src[4], Ld + ASZ + 16384 + tid * 16);
      src[4] += 128;
      gload_lds16(src[5], Ld + ASZ + 24576 + tid * 16);
      src[5] += 128;
    };

    const int NT = K >> 6;  // K-tiles of 64
    stage_a(0);
    stage_b(0);
    stage_c(0);
    stage_a(1);
    stage_b(1);
    stage_c(1);
    asm volatile("s_waitcnt vmcnt(6)" ::: "memory");
    __builtin_amdgcn_s_barrier();

    int cb0 = 0, sb = 2;
    for (int kt = 0; kt < NT; ++kt) {
      const bool pre = (kt + 2 < NT);
      if (pre) stage_a(sb);
      // kk0 cluster (stage_b issues in its MFMA shadow)
      {
        bf16x8 af[4], bf[4];
#pragma unroll
        for (int m = 0; m < 4; ++m)
          af[m] = ldfrag((const unsigned short*)(lds + cb0 + Aoff[0][m]));
#pragma unroll
        for (int n = 0; n < 4; ++n)
          bf[n] = ldfrag((const unsigned short*)(lds + cb0 + Boff[0][n]));
        if (pre) stage_b(sb);
        __builtin_amdgcn_s_setprio(1);
#pragma unroll
        for (int m = 0; m < 4; ++m)
#pragma unroll
          for (int n = 0; n < 4; ++n)
            acc[m][n] = __builtin_amdgcn_mfma_f32_16x16x32_bf16(af[m], bf[n], acc[m][n], 0, 0, 0);
        __builtin_amdgcn_s_setprio(0);
      }
      // kk1 cluster (stage_c issues in its MFMA shadow)
      {
        bf16x8 af[4], bf[4];
#pragma unroll
        for (int m = 0; m < 4; ++m)
          af[m] = ldfrag((const unsigned short*)(lds + cb0 + Aoff[1][m]));
#pragma unroll
        for (int n = 0; n < 4; ++n)
          bf[n] = ldfrag((const unsigned short*)(lds + cb0 + Boff[1][n]));
        if (pre) stage_c(sb);
        __builtin_amdgcn_s_setprio(1);
#pragma unroll
        for (int m = 0; m < 4; ++m)
#pragma unroll
          for (int n = 0; n < 4; ++n)
            acc[m][n] = __builtin_amdgcn_mfma_f32_16x16x32_bf16(af[m], bf[n], acc[m][n], 0, 0, 0);
        __builtin_amdgcn_s_setprio(0);
      }
      if (pre) {
        asm volatile("s_waitcnt vmcnt(6)" ::: "memory");  // tile t+1 published
        __builtin_amdgcn_s_barrier();
      } else if (kt + 1 < NT) {
        asm volatile("s_waitcnt vmcnt(0)" ::: "memory");
        __builtin_amdgcn_s_barrier();
      }
      cb0 += BUFSZ;
      if (cb0 == 3 * BUFSZ) cb0 = 0;
      sb += 1;
      if (sb == 3) sb = 0;
    }

    // epilogue
#pragma unroll
    for (int m = 0; m < 4; ++m) {
      const size_t row0 = am0 + wr * 64 + m * 16 + kg * 4;
#pragma unroll
      for (int n = 0; n < 4; ++n) {
        const size_t col = bn0 + wc * 64 + n * 16 + fr;
        if (EPI == 3) {
          if (bn0 < 1024) {
#pragma unroll
            for (int r = 0; r < 4; ++r) Cb[(row0 + r) * 1024 + col] = f2b(acc[m][n][r]);
          } else if (bn0 < 2048) {
#pragma unroll
            for (int r = 0; r < 4; ++r) pK[(row0 + r) * 1024 + col - 1024] = f2b(acc[m][n][r]);
          } else {
            const int c2 = (int)col - 2048;
            const int hh = c2 >> 6, dd = c2 & 63;
            const int bb = (int)(row0 >> 11), tt = (int)(row0 & 2047);
            u16x4 pv;
#pragma unroll
            for (int r = 0; r < 4; ++r) pv[r] = f2b(acc[m][n][r]);
            *(u16x4*)(pVT + (((size_t)bb * 16 + hh) * 64 + dd) * 2048 + tt) = pv;
          }
        } else {
          const float bv = (EPI >= 1) ? bias[col] : 0.f;
#pragma unroll
          for (int r = 0; r < 4; ++r) {
            const size_t idx = (row0 + r) * N + col;
            float v = acc[m][n][r] + bv;
            if (EPI == 1) v = fmaxf(v, 0.f);
            if (EPI == 2) {
              Cf[idx] = v + resid[idx];
            } else {
              Cb[idx] = f2b(v);
            }
          }
        }
      }
    }
  }
}

// ---------------- fused causal attention: fat phases (64 q/wave), R13 exact ----------------
#define PSTR 72
#define SC2 0.18033688f  /* 0.125 * log2(e) */
__global__ __launch_bounds__(256, 2) void attn_kernel(const unsigned short* __restrict__ Qb,
                                                      const unsigned short* __restrict__ Kb,
                                                      const unsigned short* __restrict__ VT,
                                                      unsigned short* __restrict__ ATT) {
  __shared__ __align__(16) char ldsK[3 * 8192];
  __shared__ __align__(16) unsigned short Pl[4][64 * PSTR];
  const int tid = threadIdx.x;
  const int w = tid >> 6, l = tid & 63;
  const int kg = l >> 4, fr = l & 15;
  const int bh = blockIdx.x;
  const int b = bh >> 4, h = bh & 15;
  const int yy = (int)blockIdx.y;
  const int qt = (yy < 4) ? 7 - yy : yy - 4;
  const int q0 = qt * 256 + w * 64;
  const size_t rbase = (size_t)b * 2048;
  const unsigned short* vtb = VT + (size_t)bh * 64 * 2048;
  const f32x4 fz = {0.f, 0.f, 0.f, 0.f};

  const int rowoff = tid >> 3;
  const int cbsw = ((tid & 7) * 16) ^ ((rowoff & 7) << 4);
  const char* ksrc = (const char*)(Kb + rbase * 1024 + h * 64) + (size_t)rowoff * 2048 + cbsw;

  int koff[4][2];
#pragma unroll
  for (int sg = 0; sg < 4; ++sg)
#pragma unroll
    for (int c = 0; c < 2; ++c)
      koff[sg][c] = (sg * 16 + fr) * 128 + ((c * 64 + kg * 16) ^ ((fr & 7) << 4));

  bf16x8 bq[4][2];
#pragma unroll
  for (int qg = 0; qg < 4; ++qg) {
    const unsigned short* qrow = Qb + (rbase + q0 + qg * 16 + fr) * 1024 + h * 64;
#pragma unroll
    for (int c = 0; c < 2; ++c) bq[qg][c] = ldfrag(qrow + c * 32 + kg * 8);
  }

  f32x4 o[4][4];
#pragma unroll
  for (int qg = 0; qg < 4; ++qg)
#pragma unroll
    for (int nd = 0; nd < 4; ++nd) o[qg][nd] = (f32x4){0.f, 0.f, 0.f, 0.f};
  float m_run2[4] = {-1e30f, -1e30f, -1e30f, -1e30f};
  float l_run[4] = {0.f, 0.f, 0.f, 0.f};

  auto stage = [&](int t, int sbuf) {
    gload_lds16(ksrc + (size_t)(t * 64) * 2048, ldsK + sbuf * 8192 + tid * 16);
    gload_lds16(ksrc + (size_t)(t * 64 + 32) * 2048, ldsK + sbuf * 8192 + 4096 + tid * 16);
  };

  auto softmax_qg = [&](int qg, int s0, f32x4 (&stq)[4]) -> float {
    const int qa = q0 + qg * 16 + fr;
    float vals[16];
    if (s0 + 63 <= q0 + qg * 16) {
#pragma unroll
      for (int sg = 0; sg < 4; ++sg)
#pragma unroll
        for (int r = 0; r < 4; ++r) vals[sg * 4 + r] = stq[sg][r];
    } else {
#pragma unroll
      for (int sg = 0; sg < 4; ++sg)
#pragma unroll
        for (int r = 0; r < 4; ++r) {
          const int sa = s0 + sg * 16 + kg * 4 + r;
          vals[sg * 4 + r] = (sa > qa) ? -1e30f : stq[sg][r];
        }
    }
    float m5[5];
#pragma unroll
    for (int i = 0; i < 5; ++i)
      m5[i] = fmaxf(fmaxf(vals[3 * i], vals[3 * i + 1]), vals[3 * i + 2]);
    const float vmax =
        fmaxf(fmaxf(fmaxf(m5[0], m5[1]), m5[2]), fmaxf(fmaxf(m5[3], m5[4]), vals[15]));
    const float tm2 = vmax * SC2;
    if (__any(tm2 > m_run2[qg] + 8.f)) {
      float tmax2 = tm2;
      tmax2 = fmaxf(tmax2, __shfl_xor(tmax2, 16));
      tmax2 = fmaxf(tmax2, __shfl_xor(tmax2, 32));
      const float m_new2 = fmaxf(m_run2[qg], tmax2);
      const float alpha = fexp2(m_run2[qg] - m_new2);
      m_run2[qg] = m_new2;
      l_run[qg] *= alpha;
      float al[4];
#pragma unroll
      for (int r = 0; r < 4; ++r) al[r] = __shfl(alpha, kg * 4 + r);
#pragma unroll
      for (int nd = 0; nd < 4; ++nd)
#pragma unroll
        for (int r = 0; r < 4; ++r) o[qg][nd][r] *= al[r];
    }
    const float nm2 = -m_run2[qg];
    float psum = 0.f;
    unsigned pk[8];
#pragma unroll
    for (int i = 0; i < 8; ++i) {
      const float p0 = fexp2(__builtin_fmaf(vals[2 * i], SC2, nm2));
      const float p1 = fexp2(__builtin_fmaf(vals[2 * i + 1], SC2, nm2));
      psum += p0 + p1;
      pk[i] = cvtpk(p0, p1);
    }
#pragma unroll
    for (int sg = 0; sg < 4; ++sg) {
      u32x2 w2 = {pk[2 * sg], pk[2 * sg + 1]};
      *(u32x2*)(&Pl[w][(qg * 16 + fr) * PSTR + sg * 16 + kg * 4]) = w2;
    }
    return psum;
  };

  auto compute = [&](int s0, int cbb) {
    if (s0 > q0 + 63) return;
    bf16x8 vb[4][2];
#pragma unroll
    for (int nd = 0; nd < 4; ++nd)
#pragma unroll
      for (int ks = 0; ks < 2; ++ks)
        vb[nd][ks] = ldfrag(vtb + (size_t)(nd * 16 + fr) * 2048 + s0 + ks * 32 + kg * 8);

    float psv[4];
#pragma unroll
    for (int qp = 0; qp < 2; ++qp) {
      f32x4 st[4][2];
#pragma unroll
      for (int sg = 0; sg < 4; ++sg) {
        const bf16x8 ka0 = ldfrag((const unsigned short*)(ldsK + cbb + koff[sg][0]));
        const bf16x8 ka1 = ldfrag((const unsigned short*)(ldsK + cbb + koff[sg][1]));
#pragma unroll
        for (int qh = 0; qh < 2; ++qh)
          st[sg][qh] = __builtin_amdgcn_mfma_f32_16x16x32_bf16(
              ka1, bq[qp * 2 + qh][1],
              __builtin_amdgcn_mfma_f32_16x16x32_bf16(ka0, bq[qp * 2 + qh][0], fz, 0, 0, 0),
              0, 0, 0);
      }
#pragma unroll
      for (int qh = 0; qh < 2; ++qh) {
        f32x4 stq[4];
#pragma unroll
        for (int sg = 0; sg < 4; ++sg) stq[sg] = st[sg][qh];
        psv[qp * 2 + qh] = softmax_qg(qp * 2 + qh, s0, stq);
      }
    }

    {
      float a[4], c[4];
#pragma unroll
      for (int qg = 0; qg < 4; ++qg) a[qg] = __shfl_xor(psv[qg], 16);
#pragma unroll
      for (int qg = 0; qg < 4; ++qg) psv[qg] += a[qg];
#pragma unroll
      for (int qg = 0; qg < 4; ++qg) c[qg] = __shfl_xor(psv[qg], 32);
#pragma unroll
      for (int qg = 0; qg < 4; ++qg) l_run[qg] += psv[qg] + c[qg];
    }

#pragma unroll
    for (int qg = 0; qg < 4; ++qg)
#pragma unroll
      for (int ks = 0; ks < 2; ++ks) {
        const bf16x8 pa = ldfrag(&Pl[w][(qg * 16 + fr) * PSTR + ks * 32 + kg * 8]);
#pragma unroll
        for (int nd = 0; nd < 4; ++nd)
          o[qg][nd] = __builtin_amdgcn_mfma_f32_16x16x32_bf16(pa, vb[nd][ks], o[qg][nd], 0, 0, 0);
      }
  };

  const int NT = 4 * qt + 4;
  stage(0, 0);
  stage(1, 1);
  asm volatile("s_waitcnt vmcnt(2)" ::: "memory");
  __builtin_amdgcn_s_barrier();
  int cb = 0, sb = 2;
  for (int t = 0; t < NT; ++t) {
    if (t + 2 < NT) stage(t + 2, sb);
    compute(t * 64, cb * 8192);
    if (t + 2 < NT) {
      asm volatile("s_waitcnt vmcnt(2)" ::: "memory");
      __builtin_amdgcn_s_barrier();
    } else if (t + 1 < NT) {
      asm volatile("s_waitcnt vmcnt(0)" ::: "memory");
      __builtin_amdgcn_s_barrier();
    }
    cb += 1; if (cb == 3) cb = 0;
    sb += 1; if (sb == 3) sb = 0;
  }

#pragma unroll
  for (int qg = 0; qg < 4; ++qg) {
    const float li = __builtin_amdgcn_rcpf(l_run[qg]);
    float linv[4];
#pragma unroll
    for (int r = 0; r < 4; ++r) linv[r] = __shfl(li, kg * 4 + r);
#pragma unroll
    for (int nd = 0; nd < 4; ++nd)
#pragma unroll
      for (int r = 0; r < 4; ++r) {
        const size_t row = rbase + q0 + qg * 16 + kg * 4 + r;
        ATT[row * 1024 + h * 64 + nd * 16 + fr] = f2b(o[qg][nd][r] * linv[r]);
      }
  }
}

// ---------------- launch ----------------
extern "C" void kernel_launch(void* const* d_in, const int* in_sizes, int n_in, void* d_out,
                              int out_size, void* d_ws, size_t ws_size, hipStream_t stream) {
  const float* x = (const float*)d_in[0];
  const float* Wk = (const float*)d_in[1];
  const float* Wq = (const float*)d_in[2];
  const float* Wv = (const float*)d_in[3];
  const float* Wproj = (const float*)d_in[4];
  const float* bproj = (const float*)d_in[5];
  const float* W1 = (const float*)d_in[6];
  const float* b1 = (const float*)d_in[7];
  const float* W2 = (const float*)d_in[8];
  const float* b2 = (const float*)d_in[9];
  const float* g1 = (const float*)d_in[10];
  const float* beta1 = (const float*)d_in[11];
  const float* g2 = (const float*)d_in[12];
  const float* beta2 = (const float*)d_in[13];
  float* out = (float*)d_out;
  unsigned short* wsu = (unsigned short*)d_ws;

  const size_t o_qkvW = 0;                           // [3072][1024]
  const size_t o_projW = o_qkvW + 3072 * 1024;       // [1024][1024]
  const size_t o_W1 = o_projW + 1024 * 1024;         // [4096][1024]
  const size_t o_W2 = o_W1 + 4096 * 1024;            // [1024][4096]
  const size_t o_H = o_W2 + 1024 * 4096;             // [8192][1024]
  const size_t o_Q = o_H + (size_t)8192 * 1024;      // [8192][1024]
  const size_t o_K = o_Q + (size_t)8192 * 1024;      // [8192][1024]
  const size_t o_VT = o_K + (size_t)8192 * 1024;     // [64][64][2048]
  const size_t o_ATT = o_VT + (size_t)8192 * 1024;   // [8192][1024]
  const size_t o_FF1 = o_Q;                          // [8192][4096] (reuses Q,K,VT,ATT)

  dim3 tpb(32, 8);
  transpose_cast<<<dim3(32, 32), tpb, 0, stream>>>(Wq, wsu + o_qkvW, 1024, 1024);
  transpose_cast<<<dim3(32, 32), tpb, 0, stream>>>(Wk, wsu + o_qkvW + 1024 * 1024, 1024, 1024);
  transpose_cast<<<dim3(32, 32), tpb, 0, stream>>>(Wv, wsu + o_qkvW + 2 * 1024 * 1024, 1024, 1024);
  transpose_cast<<<dim3(32, 32), tpb, 0, stream>>>(Wproj, wsu + o_projW, 1024, 1024);
  transpose_cast<<<dim3(128, 32), tpb, 0, stream>>>(W1, wsu + o_W1, 1024, 4096);
  transpose_cast<<<dim3(32, 128), tpb, 0, stream>>>(W2, wsu + o_W2, 4096, 1024);

  ln_kernel<<<2048, 256, 0, stream>>>(x, g1, beta1, wsu + o_H);

  // QKV: 768 tiles, grid 256 x3 rounds, EPI3 splits Q/K/V^T
  gemmS<3><<<256, 512, 0, stream>>>(wsu + o_H, wsu + o_qkvW, nullptr, nullptr, nullptr,
                                    wsu + o_Q, wsu + o_K, wsu + o_VT, 3072, 1024, 768);

  attn_kernel<<<dim3(64, 8), 256, 0, stream>>>(wsu + o_Q, wsu + o_K, wsu + o_VT, wsu + o_ATT);

  // proj: 256 tiles, grid 256 x1 round
  gemmS<2><<<256, 512, 0, stream>>>(wsu + o_ATT, wsu + o_projW, bproj, x, out, nullptr,
                                    nullptr, nullptr, 1024, 1024, 256);

  ln_kernel<<<2048, 256, 0, stream>>>(out, g2, beta2, wsu + o_H);

  // FF1: 1024 tiles, grid 256 x4 rounds
  gemmS<1><<<256, 512, 0, stream>>>(wsu + o_H, wsu + o_W1, b1, nullptr, nullptr,
                                    wsu + o_FF1, nullptr, nullptr, 4096, 1024, 1024);

  // FF2: 256 tiles, grid 256 x1 round, K=4096 (NT=64)
  gemmS<2><<<256, 512, 0, stream>>>(wsu + o_FF1, wsu + o_W2, b2, out, out, nullptr,
                                    nullptr, nullptr, 1024, 4096, 256);
}